// Round 11
// baseline (727.768 us; speedup 1.0000x reference)
//
#include <hip/hip_runtime.h>
#include <hip/hip_bf16.h>

typedef unsigned short b16;
typedef __attribute__((ext_vector_type(8))) unsigned short us8;
typedef __attribute__((ext_vector_type(8))) short short8;   // MFMA A/B frag (8 bf16)
typedef __attribute__((ext_vector_type(4))) float float4v;  // MFMA C/D frag

#define NN 100000
#define NE 600000

__device__ __forceinline__ float bf2f(b16 u) {
    return __uint_as_float(((unsigned)u) << 16);
}
__device__ __forceinline__ b16 f2bf(float f) {
    unsigned x = __float_as_uint(f);
    return (b16)((x + 0x7fffu + ((x >> 16) & 1u)) >> 16);
}

// ---------- param layout ----------
#define PB_B1 0
#define PB_B2 128
#define PB_G1 256
#define PB_BE1 384
#define PB_G2 512
#define PB_BE2 640
#define PB_G3 768
#define PB_BE3 832
#define PB_SZ 896

// ---------- fused dtype-detect + param conversion (ONE single-block launch) ----
__global__ __launch_bounds__(1024) void k_cvtall(
    const void* __restrict__ y, const void* __restrict__ ei, const void* b1,
    const void* b2, const void* g1, const void* be1, const void* g2,
    const void* be2, const void* g3, const void* be3, float* __restrict__ PB,
    int* __restrict__ flags) {
    __shared__ int f32_s;
    if (threadIdx.x == 0) {
        const b16* p = (const b16*)y;
        int f32 = 0;
        for (int i = 0; i < 128; ++i) {
            float v = bf2f(p[i]);
            if (!(fabsf(v) < 1e4f)) { f32 = 1; break; }
        }
        flags[0] = f32;
        f32_s = f32;
        const long long* q = (const long long*)ei;
        int i64 = 1;
        for (int i = 0; i < 4; ++i) {
            long long v = q[i];
            if (v < 0 || v >= NN) i64 = 0;
        }
        flags[1] = i64;
    }
    __syncthreads();
    const int f32 = f32_s;
    const void* srcs[8] = {b1, b2, g1, be1, g2, be2, g3, be3};
    for (int i = threadIdx.x; i < PB_SZ; i += 1024) {
        int seg, off;
        if (i < 768) { seg = i >> 7; off = seg << 7; }
        else if (i < 832) { seg = 6; off = 768; }
        else { seg = 7; off = 832; }
        int idx = i - off;
        const void* s = srcs[seg];
        PB[i] = f32 ? ((const float*)s)[idx] : bf2f(((const b16*)s)[idx]);
    }
}

// ---------- edge_index normalize (+ zero deg/cnt for later kernels) ----------
__global__ void k_idx(const void* __restrict__ ei, int* __restrict__ src32,
                      int* __restrict__ dst32, const int* __restrict__ flags,
                      float* __restrict__ deg, int* __restrict__ cnt) {
    int e = blockIdx.x * blockDim.x + threadIdx.x;
    if (e < NN) { deg[e] = 0.f; cnt[e] = 0; }
    if (e >= NE) return;
    int s, d;
    if (flags[1]) {
        const long long* p = (const long long*)ei;
        s = (int)p[e];
        d = (int)p[NE + e];
    } else {
        const int* p = (const int*)ei;
        s = p[e];
        d = p[NE + e];
    }
    src32[e] = ((unsigned)s < NN) ? s : 0;
    dst32[e] = ((unsigned)d < NN) ? d : 0;
}

// ---------- degree (weighted) + CSR count ----------
__global__ void k_degcnt(const int* __restrict__ dst, const void* __restrict__ ea,
                         float* __restrict__ deg, int* __restrict__ cnt,
                         const int* __restrict__ flags) {
    int e = blockIdx.x * blockDim.x + threadIdx.x;
    if (e >= NE) return;
    float w = flags[0] ? ((const float*)ea)[e] : bf2f(((const b16*)ea)[e]);
    int d = dst[e];
    unsafeAtomicAdd(&deg[d], w);
    atomicAdd(&cnt[d], 1);
}

// ---------- 2-phase exclusive scan of cnt[NN] -> rowptr[NN+1] ----------
#define SCAN_B 1024
#define SCAN_NB ((NN + SCAN_B - 1) / SCAN_B)

// also performs the deg -> rsqrt(deg) transform (was k_dis)
__global__ __launch_bounds__(SCAN_B) void k_scan1(const int* __restrict__ cnt,
                                                  int* __restrict__ inc,
                                                  int* __restrict__ bsum,
                                                  float* __restrict__ deg) {
    __shared__ int s[SCAN_B];
    int i = blockIdx.x * SCAN_B + threadIdx.x;
    if (i < NN) {
        float d = deg[i];
        deg[i] = (d > 0.f) ? rsqrtf(fmaxf(d, 1e-12f)) : 0.f;
    }
    s[threadIdx.x] = (i < NN) ? cnt[i] : 0;
    __syncthreads();
    for (int off = 1; off < SCAN_B; off <<= 1) {
        int t = (threadIdx.x >= off) ? s[threadIdx.x - off] : 0;
        __syncthreads();
        s[threadIdx.x] += t;
        __syncthreads();
    }
    if (i < NN) inc[i] = s[threadIdx.x];
    if (threadIdx.x == SCAN_B - 1) bsum[blockIdx.x] = s[SCAN_B - 1];
}

// wave 0 mask-reduces the 98 block sums in-register (replaces k_scan2 dispatch);
// also re-zeroes cnt (used as fill cursor by k_fill)
__global__ __launch_bounds__(SCAN_B) void k_scan3(const int* __restrict__ inc,
                                                  const int* __restrict__ bsum,
                                                  int* __restrict__ rowptr,
                                                  int* __restrict__ cnt) {
    __shared__ int base_s;
    const int b = blockIdx.x;
    const int tid = threadIdx.x;
    if (tid < 64) {
        int v = 0;
        if (tid < SCAN_NB && tid < b) v += bsum[tid];
        if (tid + 64 < SCAN_NB && tid + 64 < b) v += bsum[tid + 64];
#pragma unroll
        for (int off = 32; off > 0; off >>= 1) v += __shfl_down(v, off);
        if (tid == 0) base_s = v;
    }
    __syncthreads();
    const int base = base_s;
    int i = b * SCAN_B + tid;
    if (i == 0) rowptr[0] = 0;
    if (i < NN) {
        rowptr[i + 1] = inc[i] + base;
        cnt[i] = 0;
    }
}

// ---------- fill CSR: packed (weight<<32 | src) pairs ----------
__global__ void k_fill(const int* __restrict__ src, const int* __restrict__ dst,
                       const void* __restrict__ ea, const float* __restrict__ dis,
                       const int* __restrict__ rowptr, int* __restrict__ fill,
                       unsigned long long* __restrict__ pairs,
                       const int* __restrict__ flags) {
    int e = blockIdx.x * blockDim.x + threadIdx.x;
    if (e >= NE) return;
    float a = flags[0] ? ((const float*)ea)[e] : bf2f(((const b16*)ea)[e]);
    int d = dst[e];
    int s = src[e];
    int pos = rowptr[d] + atomicAdd(&fill[d], 1);
    float wgt = dis[s] * a * dis[d];
    pairs[pos] = ((unsigned long long)__float_as_uint(wgt) << 32) | (unsigned)s;
}

// ---------- pack W (fp32/bf16 [512][NC]) into B-fragment order ----------
__global__ void k_pack(const void* __restrict__ W, b16* __restrict__ Wp, int NC,
                       const int* __restrict__ flags) {
    int f = blockIdx.x * blockDim.x + threadIdx.x;
    int total = 512 * NC / 8;
    if (f >= total) return;
    int lane = f & 63;
    int rest = f >> 6;
    int CT = NC >> 4;
    int ct = rest % CT, ks = rest / CT;
    int k0 = 32 * ks + (lane >> 4) * 8;
    int col = 16 * ct + (lane & 15);
    us8 v;
#pragma unroll
    for (int j = 0; j < 8; ++j) {
        float x = flags[0] ? ((const float*)W)[(size_t)(k0 + j) * NC + col]
                           : bf2f(((const b16*)W)[(size_t)(k0 + j) * NC + col]);
        v[j] = f2bf(x);
    }
    *(us8*)&Wp[(size_t)f * 8] = v;
}

// ---------- pack W3 (4 matrices of 128x64) as one 128x256 B, frag order ----------
__global__ void k_pack3(const void* __restrict__ W, b16* __restrict__ Bp,
                        const int* __restrict__ flags) {
    int f = blockIdx.x * blockDim.x + threadIdx.x;
    if (f >= 4096) return;
    int lane = f & 63;
    int rest = f >> 6;
    int ct = rest & 15, ks = rest >> 4;
    int k0 = 32 * ks + (lane >> 4) * 8;
    int cp = 16 * ct + (lane & 15);
    int km = cp >> 6, c = cp & 63;
    us8 v;
#pragma unroll
    for (int j = 0; j < 8; ++j) {
        size_t idx = (size_t)(km * 128 + k0 + j) * 64 + c;
        float x = flags[0] ? ((const float*)W)[idx] : bf2f(((const b16*)W)[idx]);
        v[j] = f2bf(x);
    }
    *(us8*)&Bp[(size_t)f * 8] = v;
}

// ---------- initial cast y -> XC cols [0,128); also zero per-layer BN stats ----
__global__ void k_cast(const void* __restrict__ y, b16* __restrict__ XC,
                       const int* __restrict__ flags, float* __restrict__ gstat) {
    int i = blockIdx.x * blockDim.x + threadIdx.x;
    if (i < 768) gstat[i] = 0.f;  // 3 layers x (128 sum + 128 sq)
    if (i >= NN * 32) return;
    int row = i >> 5, cg = i & 31;
    float4 v;
    if (flags[0]) {
        v = ((const float4*)y)[i];
    } else {
        ushort4 u = ((const ushort4*)y)[i];
        v = make_float4(bf2f(u.x), bf2f(u.y), bf2f(u.z), bf2f(u.w));
    }
    ushort4 o;
    o.x = f2bf(v.x); o.y = f2bf(v.y); o.z = f2bf(v.z); o.w = f2bf(v.w);
    *(ushort4*)&XC[(size_t)row * 512 + 4 * cg] = o;
}

// ---------- SpMM gather (128 cols): XC[ci,ci+128) -> XC[co,co+128) ----------
__global__ __launch_bounds__(256) void k_spmm(b16* __restrict__ XC, int ci, int co,
                                              const int* __restrict__ rowptr,
                                              const unsigned long long* __restrict__ pairs) {
    int gid = blockIdx.x * blockDim.x + threadIdx.x;
    int node = gid >> 6;
    if (node >= NN) return;
    int lane = gid & 63;
    int grp = lane >> 4;  // edge slot group 0..3
    int l15 = lane & 15;  // 16B chunk within 256B segment
    int beg = rowptr[node], end = rowptr[node + 1];

    float a0[8], a1[8];
#pragma unroll
    for (int j = 0; j < 8; ++j) {
        a0[j] = 0.f;
        a1[j] = 0.f;
    }
    for (int i = beg; i < end; i += 8) {
        int e0 = i + grp, e1 = e0 + 4;
        int lim = end - 1;
        unsigned long long p0 = pairs[e0 < lim ? e0 : lim];
        unsigned long long p1 = pairs[e1 < lim ? e1 : lim];
        float w0 = (e0 < end) ? __uint_as_float((unsigned)(p0 >> 32)) : 0.f;
        float w1 = (e1 < end) ? __uint_as_float((unsigned)(p1 >> 32)) : 0.f;
        int s0 = (int)(p0 & 0xffffffffu);
        int s1 = (int)(p1 & 0xffffffffu);
        us8 u0 = *(const us8*)&XC[(size_t)s0 * 512 + ci + 8 * l15];
        us8 u1 = *(const us8*)&XC[(size_t)s1 * 512 + ci + 8 * l15];
#pragma unroll
        for (int j = 0; j < 8; ++j) {
            a0[j] = fmaf(w0, bf2f(u0[j]), a0[j]);
            a1[j] = fmaf(w1, bf2f(u1[j]), a1[j]);
        }
    }
#pragma unroll
    for (int j = 0; j < 8; ++j) a0[j] += a1[j];
#pragma unroll
    for (int j = 0; j < 8; ++j) a0[j] += __shfl_xor(a0[j], 16);
#pragma unroll
    for (int j = 0; j < 8; ++j) a0[j] += __shfl_xor(a0[j], 32);
    if (grp == 0) {
        us8 o;
#pragma unroll
        for (int j = 0; j < 8; ++j) o[j] = f2bf(a0[j]);
        *(us8*)&XC[(size_t)node * 512 + co + 8 * l15] = o;
    }
}

// ---------- SpMM gather (64 cols) + fused z-add: D = A*G + Z[:,zoff..] ----------
__global__ __launch_bounds__(256) void k_spmm64(const b16* __restrict__ G, int gstride,
                                                int gcol, const b16* __restrict__ Z,
                                                int zoff, b16* __restrict__ D,
                                                const int* __restrict__ rowptr,
                                                const unsigned long long* __restrict__ pairs) {
    int gid = blockIdx.x * blockDim.x + threadIdx.x;
    int node = gid >> 6;
    if (node >= NN) return;
    int lane = gid & 63;
    int grp = lane >> 4;
    int l15 = lane & 15;  // 8B chunk (4 bf16) within 128B segment
    int beg = rowptr[node], end = rowptr[node + 1];

    float a0[4], a1[4];
#pragma unroll
    for (int j = 0; j < 4; ++j) {
        a0[j] = 0.f;
        a1[j] = 0.f;
    }
    for (int i = beg; i < end; i += 8) {
        int e0 = i + grp, e1 = e0 + 4;
        int lim = end - 1;
        unsigned long long p0 = pairs[e0 < lim ? e0 : lim];
        unsigned long long p1 = pairs[e1 < lim ? e1 : lim];
        float w0 = (e0 < end) ? __uint_as_float((unsigned)(p0 >> 32)) : 0.f;
        float w1 = (e1 < end) ? __uint_as_float((unsigned)(p1 >> 32)) : 0.f;
        int s0 = (int)(p0 & 0xffffffffu);
        int s1 = (int)(p1 & 0xffffffffu);
        ushort4 u0 = *(const ushort4*)&G[(size_t)s0 * gstride + gcol + 4 * l15];
        ushort4 u1 = *(const ushort4*)&G[(size_t)s1 * gstride + gcol + 4 * l15];
        a0[0] = fmaf(w0, bf2f(u0.x), a0[0]);
        a0[1] = fmaf(w0, bf2f(u0.y), a0[1]);
        a0[2] = fmaf(w0, bf2f(u0.z), a0[2]);
        a0[3] = fmaf(w0, bf2f(u0.w), a0[3]);
        a1[0] = fmaf(w1, bf2f(u1.x), a1[0]);
        a1[1] = fmaf(w1, bf2f(u1.y), a1[1]);
        a1[2] = fmaf(w1, bf2f(u1.z), a1[2]);
        a1[3] = fmaf(w1, bf2f(u1.w), a1[3]);
    }
#pragma unroll
    for (int j = 0; j < 4; ++j) a0[j] += a1[j];
#pragma unroll
    for (int j = 0; j < 4; ++j) a0[j] += __shfl_xor(a0[j], 16);
#pragma unroll
    for (int j = 0; j < 4; ++j) a0[j] += __shfl_xor(a0[j], 32);
    if (grp == 0) {
        ushort4 z = *(const ushort4*)&Z[(size_t)node * 256 + zoff + 4 * l15];
        ushort4 o;
        o.x = f2bf(a0[0] + bf2f(z.x));
        o.y = f2bf(a0[1] + bf2f(z.y));
        o.z = f2bf(a0[2] + bf2f(z.z));
        o.w = f2bf(a0[3] + bf2f(z.w));
        *(ushort4*)&D[(size_t)node * 64 + 4 * l15] = o;
    }
}

// ---------- MFMA GEMM + fused BN-stat epilogue ----------
// v11: wave = 64 rows x NC cols (acc[4][CT]), block = 2 waves = 128 rows,
// grid 782. Rationale (round-10 counters): per-wave MFMA cover per k-step was
// 16 MFMA (~130cy) vs ~500cy A-latency at 3 waves/SIMD -> ~6% MfmaUtil. This
// doubles per-wave MFMA cover to 32/k-step and halves wave count (B L2 traffic
// halves too). VGPR ~240 (acc 128 + frags 96); risk = prefetch sink or spill —
// counters (VGPR_Count, scratch, MfmaUtil) diagnose which.
template <int NC>
__global__ __launch_bounds__(128) void k_mgemm(const b16* __restrict__ XC,
                                               const b16* __restrict__ Wp,
                                               const float* __restrict__ bias,
                                               b16* __restrict__ OUT,
                                               float* __restrict__ gsum,
                                               float* __restrict__ gsq) {
    constexpr int CT = NC / 16;
    __shared__ float csum[NC], csq[NC];
    const int tid = threadIdx.x;
    const int wave = tid >> 6;
    const int lane = tid & 63;
    const int quad = lane >> 4;
    const int l15 = lane & 15;
    const int rbase = blockIdx.x * 128 + wave * 64;

    for (int i = tid; i < NC; i += 128) {
        csum[i] = 0.f;
        csq[i] = 0.f;
    }

    float4v acc[4][CT];
#pragma unroll
    for (int rt = 0; rt < 4; ++rt)
#pragma unroll
        for (int ct = 0; ct < CT; ++ct) acc[rt][ct] = (float4v)(0.f);

    const b16* gA[4];
#pragma unroll
    for (int rt = 0; rt < 4; ++rt) {
        int r = rbase + 16 * rt + l15;
        if (r >= NN) r = NN - 1;  // clamp; dead rows excluded from store/stats
        gA[rt] = XC + (size_t)r * 512 + quad * 8;
    }
    const b16* gB = Wp + lane * 8;

    short8 afc[4], bfc[CT], afn[4], bfn[CT];
#pragma unroll
    for (int rt = 0; rt < 4; ++rt) afc[rt] = *(const short8*)(gA[rt]);
#pragma unroll
    for (int ct = 0; ct < CT; ++ct) bfc[ct] = *(const short8*)(gB + ct * 512);

    for (int ks = 0; ks < 16; ++ks) {
        if (ks < 15) {  // prefetch next k-step into regs (issues before MFMA waits)
#pragma unroll
            for (int rt = 0; rt < 4; ++rt)
                afn[rt] = *(const short8*)(gA[rt] + 32 * (ks + 1));
#pragma unroll
            for (int ct = 0; ct < CT; ++ct)
                bfn[ct] = *(const short8*)(gB + (size_t)((ks + 1) * CT + ct) * 512);
        }
#pragma unroll
        for (int rt = 0; rt < 4; ++rt)
#pragma unroll
            for (int ct = 0; ct < CT; ++ct)
                acc[rt][ct] = __builtin_amdgcn_mfma_f32_16x16x32_bf16(
                    afc[rt], bfc[ct], acc[rt][ct], 0, 0, 0);
        if (ks < 15) {
#pragma unroll
            for (int rt = 0; rt < 4; ++rt) afc[rt] = afn[rt];
#pragma unroll
            for (int ct = 0; ct < CT; ++ct) bfc[ct] = bfn[ct];
        }
    }

    // epilogue: bf16 store + BN stats (C/D: col=lane&15, row=quad*4+reg)
#pragma unroll
    for (int rt = 0; rt < 4; ++rt) {
#pragma unroll
        for (int ct = 0; ct < CT; ++ct) {
            int col = 16 * ct + l15;
            float bv = bias ? bias[col] : 0.f;
            float s = 0.f, sq = 0.f;
#pragma unroll
            for (int r = 0; r < 4; ++r) {
                int row = rbase + 16 * rt + quad * 4 + r;
                if (row < NN) {
                    float v = acc[rt][ct][r] + bv;
                    OUT[(size_t)row * NC + col] = f2bf(v);
                    s += v;
                    sq += v * v;
                }
            }
            s += __shfl_xor(s, 16);
            s += __shfl_xor(s, 32);
            sq += __shfl_xor(sq, 16);
            sq += __shfl_xor(sq, 32);
            if (quad == 0) {
                atomicAdd(&csum[col], s);
                atomicAdd(&csq[col], sq);
            }
        }
    }
    __syncthreads();
    for (int i = tid; i < NC; i += 128) {
        unsafeAtomicAdd(&gsum[i], csum[i]);
        unsafeAtomicAdd(&gsq[i], csq[i]);
    }
}

// ---------- Z = XC[:,0:128) @ Bp (128x256, packed)  [layer-3 Horner pre-GEMM] --
__global__ __launch_bounds__(256) void k_zgemm(const b16* __restrict__ XC,
                                               const b16* __restrict__ Bp,
                                               b16* __restrict__ Z) {
    const int tid = threadIdx.x;
    const int wave = tid >> 6;
    const int lane = tid & 63;
    const int quad = lane >> 4;
    const int l15 = lane & 15;
    const int wr = wave >> 1;
    const int wc = wave & 1;
    const int rbase = blockIdx.x * 64 + wr * 32;

    float4v acc[2][8];
#pragma unroll
    for (int rt = 0; rt < 2; ++rt)
#pragma unroll
        for (int ct = 0; ct < 8; ++ct) acc[rt][ct] = (float4v)(0.f);

    const b16* gA[2];
#pragma unroll
    for (int rt = 0; rt < 2; ++rt) {
        int r = rbase + 16 * rt + l15;
        if (r >= NN) r = NN - 1;
        gA[rt] = XC + (size_t)r * 512 + quad * 8;
    }
    const b16* gB = Bp + ((size_t)(wc * 8) * 64 + lane) * 8;

    short8 afc[2], bfc[8], afn[2], bfn[8];
#pragma unroll
    for (int rt = 0; rt < 2; ++rt) afc[rt] = *(const short8*)(gA[rt]);
#pragma unroll
    for (int ct = 0; ct < 8; ++ct) bfc[ct] = *(const short8*)(gB + ct * 512);

    for (int ks = 0; ks < 4; ++ks) {
        if (ks < 3) {
#pragma unroll
            for (int rt = 0; rt < 2; ++rt)
                afn[rt] = *(const short8*)(gA[rt] + 32 * (ks + 1));
#pragma unroll
            for (int ct = 0; ct < 8; ++ct)
                bfn[ct] = *(const short8*)(gB + (size_t)((ks + 1) * 16 + ct) * 512);
        }
#pragma unroll
        for (int rt = 0; rt < 2; ++rt)
#pragma unroll
            for (int ct = 0; ct < 8; ++ct)
                acc[rt][ct] = __builtin_amdgcn_mfma_f32_16x16x32_bf16(
                    afc[rt], bfc[ct], acc[rt][ct], 0, 0, 0);
        if (ks < 3) {
#pragma unroll
            for (int rt = 0; rt < 2; ++rt) afc[rt] = afn[rt];
#pragma unroll
            for (int ct = 0; ct < 8; ++ct) bfc[ct] = bfn[ct];
        }
    }

#pragma unroll
    for (int rt = 0; rt < 2; ++rt) {
#pragma unroll
        for (int ct = 0; ct < 8; ++ct) {
            int col = 16 * (wc * 8 + ct) + l15;
#pragma unroll
            for (int r = 0; r < 4; ++r) {
                int row = rbase + 16 * rt + quad * 4 + r;
                if (row < NN) Z[(size_t)row * 256 + col] = f2bf(acc[rt][ct][r]);
            }
        }
    }
}

// ---------- column stats of compact NN x 64 bf16 buffer -> gsum/gsq ----------
__global__ __launch_bounds__(256) void k_stat64(const b16* __restrict__ T,
                                                float* __restrict__ gsum,
                                                float* __restrict__ gsq) {
    __shared__ float cs[64], cq[64];
    const int tid = threadIdx.x;
    if (tid < 64) { cs[tid] = 0.f; cq[tid] = 0.f; }
    __syncthreads();
    const int gt = blockIdx.x * 256 + tid;
    const int stride = gridDim.x * 256;  // multiple of 8 -> octet fixed per thread
    float s[8], q[8];
#pragma unroll
    for (int j = 0; j < 8; ++j) { s[j] = 0.f; q[j] = 0.f; }
    for (int ch = gt; ch < NN * 8; ch += stride) {
        us8 u = *(const us8*)&T[(size_t)ch * 8];
#pragma unroll
        for (int j = 0; j < 8; ++j) {
            float v = bf2f(u[j]);
            s[j] += v;
            q[j] += v * v;
        }
    }
#pragma unroll
    for (int j = 0; j < 8; ++j) {
        s[j] += __shfl_xor(s[j], 8);
        s[j] += __shfl_xor(s[j], 16);
        s[j] += __shfl_xor(s[j], 32);
        q[j] += __shfl_xor(q[j], 8);
        q[j] += __shfl_xor(q[j], 16);
        q[j] += __shfl_xor(q[j], 32);
    }
    const int lane = tid & 63;
    if (lane < 8) {
        const int c0 = lane * 8;  // lane&7 == octet id after butterfly
#pragma unroll
        for (int j = 0; j < 8; ++j) {
            atomicAdd(&cs[c0 + j], s[j]);
            atomicAdd(&cq[c0 + j], q[j]);
        }
    }
    __syncthreads();
    if (tid < 64) {
        unsafeAtomicAdd(&gsum[tid], cs[tid]);
        unsafeAtomicAdd(&gsq[tid], cq[tid]);
    }
}

// ---------- BN-apply layers 1,2 (fused param compute): OUT -> XC cols [0,128) --
__global__ __launch_bounds__(256) void k_bnapply_mid(
    const b16* __restrict__ OUT, const float* __restrict__ gsum,
    const float* __restrict__ gsq, const float* __restrict__ g,
    const float* __restrict__ be, b16* __restrict__ XC) {
    __shared__ float sc[128], sh[128];
    const int tid = threadIdx.x;
    if (tid < 128) {
        float m = gsum[tid] * (1.f / NN);
        float v = gsq[tid] * (1.f / NN) - m * m;
        v = fmaxf(v, 0.f);
        float s = rsqrtf(v + 1e-5f) * g[tid];
        sc[tid] = s;
        sh[tid] = be[tid] - m * s;
    }
    __syncthreads();
    int i = blockIdx.x * 256 + tid;
    if (i >= NN * 16) return;
    int row = i >> 4, c0 = (i & 15) * 8;
    us8 u = *(const us8*)&OUT[(size_t)row * 128 + c0];
    us8 o;
#pragma unroll
    for (int j = 0; j < 8; ++j) {
        float a = fmaf(bf2f(u[j]), sc[c0 + j], sh[c0 + j]);
        a = a > 0.f ? a : 0.01f * a;
        o[j] = f2bf(a);
    }
    *(us8*)&XC[(size_t)row * 512 + c0] = o;
}

// ---------- BN-apply layer 3 (fused param compute): T (NN x 64) -> d_out ----------
__global__ __launch_bounds__(256) void k_bnapply_last(
    const b16* __restrict__ T, const float* __restrict__ gsum,
    const float* __restrict__ gsq, const float* __restrict__ g,
    const float* __restrict__ be, void* __restrict__ dout,
    const int* __restrict__ flags) {
    __shared__ float sc[64], sh[64];
    const int tid = threadIdx.x;
    if (tid < 64) {
        float m = gsum[tid] * (1.f / NN);
        float v = gsq[tid] * (1.f / NN) - m * m;
        v = fmaxf(v, 0.f);
        float s = rsqrtf(v + 1e-5f) * g[tid];
        sc[tid] = s;
        sh[tid] = be[tid] - m * s;
    }
    __syncthreads();
    int i = blockIdx.x * 256 + tid;
    if (i >= NN * 8) return;
    int c0 = (i & 7) * 8;
    us8 u = *(const us8*)&T[(size_t)i * 8];
    float v[8];
#pragma unroll
    for (int j = 0; j < 8; ++j) {
        float a = fmaf(bf2f(u[j]), sc[c0 + j], sh[c0 + j]);
        v[j] = a > 0.f ? a : 0.01f * a;
    }
    if (flags[0]) {
        float4* d = (float4*)dout;
        d[i * 2] = make_float4(v[0], v[1], v[2], v[3]);
        d[i * 2 + 1] = make_float4(v[4], v[5], v[6], v[7]);
    } else {
        us8 o;
#pragma unroll
        for (int j = 0; j < 8; ++j) o[j] = f2bf(v[j]);
        *(us8*)&((b16*)dout)[(size_t)i * 8] = o;
    }
}

// ---------- driver ----------
extern "C" void kernel_launch(void* const* d_in, const int* in_sizes, int n_in,
                              void* d_out, int out_size, void* d_ws, size_t ws_size,
                              hipStream_t stream) {
    const void* y   = d_in[0];
    const void* ei  = d_in[1];
    const void* ea  = d_in[2];
    const void* W1  = d_in[3];
    const void* b1  = d_in[4];
    const void* g1  = d_in[5];
    const void* be1 = d_in[6];
    const void* W2  = d_in[7];
    const void* b2  = d_in[8];
    const void* g2  = d_in[9];
    const void* be2 = d_in[10];
    const void* W3  = d_in[11];
    const void* g3  = d_in[12];
    const void* be3 = d_in[13];

    char* w = (char*)d_ws;
    size_t used = 0;
    auto carve = [&](size_t bytes) -> char* {
        char* p = w + used;
        used += (bytes + 255) & ~(size_t)255;
        return p;
    };

    int* flags   = (int*)carve(16);
    int* src32   = (int*)carve((size_t)NE * 4);
    int* dst32   = (int*)carve((size_t)NE * 4);
    float* deg   = (float*)carve((size_t)NN * 4);
    int* cnt     = (int*)carve((size_t)NN * 4);
    int* rowptr  = (int*)carve((size_t)(NN + 1) * 4);
    int* cscan   = (int*)carve((size_t)NN * 4);
    int* bsum    = (int*)carve((size_t)SCAN_NB * 4);
    unsigned long long* pairs = (unsigned long long*)carve((size_t)NE * 8);
    float* PB    = (float*)carve(PB_SZ * 4);
    b16* Wp1     = (b16*)carve((size_t)512 * 128 * 2);
    b16* Wp2     = (b16*)carve((size_t)512 * 128 * 2);
    b16* Wp3c    = (b16*)carve((size_t)128 * 256 * 2);
    b16* OUT     = (b16*)carve((size_t)NN * 128 * 2);
    float* gstat = (float*)carve(768 * 4);  // 3 layers x (128 sum + 128 sq)
    b16* XC      = (b16*)carve((size_t)NN * 512 * 2);
    b16* Z       = (b16*)carve((size_t)NN * 256 * 2);  // z0|z1|z2|z3 (64 cols each)
    b16* T0      = (b16*)carve((size_t)NN * 64 * 2);
    b16* T1      = (b16*)carve((size_t)NN * 64 * 2);

    // ----- fused detect + param normalize; weight pack -----
    k_cvtall<<<1, 1024, 0, stream>>>(y, ei, b1, b2, g1, be1, g2, be2, g3, be3, PB,
                                     flags);
    k_pack<<<(512 * 128 / 8 + 255) / 256, 256, 0, stream>>>(W1, Wp1, 128, flags);
    k_pack<<<(512 * 128 / 8 + 255) / 256, 256, 0, stream>>>(W2, Wp2, 128, flags);
    k_pack3<<<16, 256, 0, stream>>>(W3, Wp3c, flags);

    // ----- graph prep -----
    k_idx<<<(NE + 255) / 256, 256, 0, stream>>>(ei, src32, dst32, flags, deg, cnt);
    k_degcnt<<<(NE + 255) / 256, 256, 0, stream>>>(dst32, ea, deg, cnt, flags);
    k_scan1<<<SCAN_NB, SCAN_B, 0, stream>>>(cnt, cscan, bsum, deg);
    k_scan3<<<SCAN_NB, SCAN_B, 0, stream>>>(cscan, bsum, rowptr, cnt);
    k_fill<<<(NE + 255) / 256, 256, 0, stream>>>(src32, dst32, ea, deg, rowptr, cnt,
                                                 pairs, flags);

    // ----- layers -----
    k_cast<<<(NN * 32 + 255) / 256, 256, 0, stream>>>(y, XC, flags, gstat);

    const int spmm_grid = (NN * 64 + 255) / 256;
    auto spmm = [&](int ci, int co) {
        k_spmm<<<spmm_grid, 256, 0, stream>>>(XC, ci, co, rowptr, pairs);
    };
    const int gemm_grid = (NN + 127) / 128;

    // layers 1,2: hops then fused GEMM over [x|Ax|A2x|A3x]; BN-apply recomputes
    // params per block (no separate k_bnparam dispatch)
    auto layer12 = [&](int li, const b16* Wp, const float* bias, const float* g,
                       const float* be) {
        spmm(0, 128);
        spmm(128, 256);
        spmm(256, 384);
        float* gs = gstat + li * 256;
        float* gq = gs + 128;
        k_mgemm<128><<<gemm_grid, 128, 0, stream>>>(XC, Wp, bias, OUT, gs, gq);
        k_bnapply_mid<<<(NN * 16 + 255) / 256, 256, 0, stream>>>(OUT, gs, gq, g, be,
                                                                 XC);
    };
    layer12(0, Wp1, PB + PB_B1, PB + PB_G1, PB + PB_BE1);
    layer12(1, Wp2, PB + PB_B2, PB + PB_G2, PB + PB_BE2);

    // layer 3 (Horner): z=[z0..z3]=x@W3cat; h=z3; h=A*h+z2; h=A*h+z1; h=A*h+z0
    k_zgemm<<<(NN + 63) / 64, 256, 0, stream>>>(XC, Wp3c, Z);
    k_spmm64<<<spmm_grid, 256, 0, stream>>>(Z, 256, 192, Z, 128, T0, rowptr, pairs);
    k_spmm64<<<spmm_grid, 256, 0, stream>>>(T0, 64, 0, Z, 64, T1, rowptr, pairs);
    k_spmm64<<<spmm_grid, 256, 0, stream>>>(T1, 64, 0, Z, 0, T0, rowptr, pairs);
    float* gs3 = gstat + 512;
    float* gq3 = gstat + 640;
    k_stat64<<<256, 256, 0, stream>>>(T0, gs3, gq3);
    k_bnapply_last<<<(NN * 8 + 255) / 256, 256, 0, stream>>>(T0, gs3, gq3, PB + PB_G3,
                                                             PB + PB_BE3, d_out, flags);
}

// Round 12
// 697.448 us; speedup vs baseline: 1.0435x; 1.0435x over previous
//
#include <hip/hip_runtime.h>
#include <hip/hip_bf16.h>

typedef unsigned short b16;
typedef __attribute__((ext_vector_type(8))) unsigned short us8;
typedef __attribute__((ext_vector_type(8))) short short8;   // MFMA A/B frag (8 bf16)
typedef __attribute__((ext_vector_type(4))) float float4v;  // MFMA C/D frag

#define NN 100000
#define NE 600000

__device__ __forceinline__ float bf2f(b16 u) {
    return __uint_as_float(((unsigned)u) << 16);
}
__device__ __forceinline__ b16 f2bf(float f) {
    unsigned x = __float_as_uint(f);
    return (b16)((x + 0x7fffu + ((x >> 16) & 1u)) >> 16);
}

// ---------- param layout ----------
#define PB_B1 0
#define PB_B2 128
#define PB_G1 256
#define PB_BE1 384
#define PB_G2 512
#define PB_BE2 640
#define PB_G3 768
#define PB_BE3 832
#define PB_SZ 896

// ---------- fused dtype-detect + param conversion (ONE single-block launch) ----
__global__ __launch_bounds__(1024) void k_cvtall(
    const void* __restrict__ y, const void* __restrict__ ei, const void* b1,
    const void* b2, const void* g1, const void* be1, const void* g2,
    const void* be2, const void* g3, const void* be3, float* __restrict__ PB,
    int* __restrict__ flags) {
    __shared__ int f32_s;
    if (threadIdx.x == 0) {
        const b16* p = (const b16*)y;
        int f32 = 0;
        for (int i = 0; i < 128; ++i) {
            float v = bf2f(p[i]);
            if (!(fabsf(v) < 1e4f)) { f32 = 1; break; }
        }
        flags[0] = f32;
        f32_s = f32;
        const long long* q = (const long long*)ei;
        int i64 = 1;
        for (int i = 0; i < 4; ++i) {
            long long v = q[i];
            if (v < 0 || v >= NN) i64 = 0;
        }
        flags[1] = i64;
    }
    __syncthreads();
    const int f32 = f32_s;
    const void* srcs[8] = {b1, b2, g1, be1, g2, be2, g3, be3};
    for (int i = threadIdx.x; i < PB_SZ; i += 1024) {
        int seg, off;
        if (i < 768) { seg = i >> 7; off = seg << 7; }
        else if (i < 832) { seg = 6; off = 768; }
        else { seg = 7; off = 832; }
        int idx = i - off;
        const void* s = srcs[seg];
        PB[i] = f32 ? ((const float*)s)[idx] : bf2f(((const b16*)s)[idx]);
    }
}

// ---------- edge_index normalize (+ zero deg/cnt for later kernels) ----------
__global__ void k_idx(const void* __restrict__ ei, int* __restrict__ src32,
                      int* __restrict__ dst32, const int* __restrict__ flags,
                      float* __restrict__ deg, int* __restrict__ cnt) {
    int e = blockIdx.x * blockDim.x + threadIdx.x;
    if (e < NN) { deg[e] = 0.f; cnt[e] = 0; }
    if (e >= NE) return;
    int s, d;
    if (flags[1]) {
        const long long* p = (const long long*)ei;
        s = (int)p[e];
        d = (int)p[NE + e];
    } else {
        const int* p = (const int*)ei;
        s = p[e];
        d = p[NE + e];
    }
    src32[e] = ((unsigned)s < NN) ? s : 0;
    dst32[e] = ((unsigned)d < NN) ? d : 0;
}

// ---------- degree (weighted) + CSR count ----------
__global__ void k_degcnt(const int* __restrict__ dst, const void* __restrict__ ea,
                         float* __restrict__ deg, int* __restrict__ cnt,
                         const int* __restrict__ flags) {
    int e = blockIdx.x * blockDim.x + threadIdx.x;
    if (e >= NE) return;
    float w = flags[0] ? ((const float*)ea)[e] : bf2f(((const b16*)ea)[e]);
    int d = dst[e];
    unsafeAtomicAdd(&deg[d], w);
    atomicAdd(&cnt[d], 1);
}

// ---------- 2-phase exclusive scan of cnt[NN] -> rowptr[NN+1] ----------
#define SCAN_B 1024
#define SCAN_NB ((NN + SCAN_B - 1) / SCAN_B)

// also performs the deg -> rsqrt(deg) transform (was k_dis)
__global__ __launch_bounds__(SCAN_B) void k_scan1(const int* __restrict__ cnt,
                                                  int* __restrict__ inc,
                                                  int* __restrict__ bsum,
                                                  float* __restrict__ deg) {
    __shared__ int s[SCAN_B];
    int i = blockIdx.x * SCAN_B + threadIdx.x;
    if (i < NN) {
        float d = deg[i];
        deg[i] = (d > 0.f) ? rsqrtf(fmaxf(d, 1e-12f)) : 0.f;
    }
    s[threadIdx.x] = (i < NN) ? cnt[i] : 0;
    __syncthreads();
    for (int off = 1; off < SCAN_B; off <<= 1) {
        int t = (threadIdx.x >= off) ? s[threadIdx.x - off] : 0;
        __syncthreads();
        s[threadIdx.x] += t;
        __syncthreads();
    }
    if (i < NN) inc[i] = s[threadIdx.x];
    if (threadIdx.x == SCAN_B - 1) bsum[blockIdx.x] = s[SCAN_B - 1];
}

// wave 0 mask-reduces the 98 block sums in-register (replaces k_scan2 dispatch);
// also re-zeroes cnt (used as fill cursor by k_fill)
__global__ __launch_bounds__(SCAN_B) void k_scan3(const int* __restrict__ inc,
                                                  const int* __restrict__ bsum,
                                                  int* __restrict__ rowptr,
                                                  int* __restrict__ cnt) {
    __shared__ int base_s;
    const int b = blockIdx.x;
    const int tid = threadIdx.x;
    if (tid < 64) {
        int v = 0;
        if (tid < SCAN_NB && tid < b) v += bsum[tid];
        if (tid + 64 < SCAN_NB && tid + 64 < b) v += bsum[tid + 64];
#pragma unroll
        for (int off = 32; off > 0; off >>= 1) v += __shfl_down(v, off);
        if (tid == 0) base_s = v;
    }
    __syncthreads();
    const int base = base_s;
    int i = b * SCAN_B + tid;
    if (i == 0) rowptr[0] = 0;
    if (i < NN) {
        rowptr[i + 1] = inc[i] + base;
        cnt[i] = 0;
    }
}

// ---------- fill CSR: packed (weight<<32 | src) pairs ----------
__global__ void k_fill(const int* __restrict__ src, const int* __restrict__ dst,
                       const void* __restrict__ ea, const float* __restrict__ dis,
                       const int* __restrict__ rowptr, int* __restrict__ fill,
                       unsigned long long* __restrict__ pairs,
                       const int* __restrict__ flags) {
    int e = blockIdx.x * blockDim.x + threadIdx.x;
    if (e >= NE) return;
    float a = flags[0] ? ((const float*)ea)[e] : bf2f(((const b16*)ea)[e]);
    int d = dst[e];
    int s = src[e];
    int pos = rowptr[d] + atomicAdd(&fill[d], 1);
    float wgt = dis[s] * a * dis[d];
    pairs[pos] = ((unsigned long long)__float_as_uint(wgt) << 32) | (unsigned)s;
}

// ---------- pack W (fp32/bf16 [512][NC]) into B-fragment order ----------
__global__ void k_pack(const void* __restrict__ W, b16* __restrict__ Wp, int NC,
                       const int* __restrict__ flags) {
    int f = blockIdx.x * blockDim.x + threadIdx.x;
    int total = 512 * NC / 8;
    if (f >= total) return;
    int lane = f & 63;
    int rest = f >> 6;
    int CT = NC >> 4;
    int ct = rest % CT, ks = rest / CT;
    int k0 = 32 * ks + (lane >> 4) * 8;
    int col = 16 * ct + (lane & 15);
    us8 v;
#pragma unroll
    for (int j = 0; j < 8; ++j) {
        float x = flags[0] ? ((const float*)W)[(size_t)(k0 + j) * NC + col]
                           : bf2f(((const b16*)W)[(size_t)(k0 + j) * NC + col]);
        v[j] = f2bf(x);
    }
    *(us8*)&Wp[(size_t)f * 8] = v;
}

// ---------- pack W3 (4 matrices of 128x64) as one 128x256 B, frag order ----------
__global__ void k_pack3(const void* __restrict__ W, b16* __restrict__ Bp,
                        const int* __restrict__ flags) {
    int f = blockIdx.x * blockDim.x + threadIdx.x;
    if (f >= 4096) return;
    int lane = f & 63;
    int rest = f >> 6;
    int ct = rest & 15, ks = rest >> 4;
    int k0 = 32 * ks + (lane >> 4) * 8;
    int cp = 16 * ct + (lane & 15);
    int km = cp >> 6, c = cp & 63;
    us8 v;
#pragma unroll
    for (int j = 0; j < 8; ++j) {
        size_t idx = (size_t)(km * 128 + k0 + j) * 64 + c;
        float x = flags[0] ? ((const float*)W)[idx] : bf2f(((const b16*)W)[idx]);
        v[j] = f2bf(x);
    }
    *(us8*)&Bp[(size_t)f * 8] = v;
}

// ---------- initial cast y -> XC cols [0,128); also zero per-layer BN stats ----
__global__ void k_cast(const void* __restrict__ y, b16* __restrict__ XC,
                       const int* __restrict__ flags, float* __restrict__ gstat) {
    int i = blockIdx.x * blockDim.x + threadIdx.x;
    if (i < 768) gstat[i] = 0.f;  // 3 layers x (128 sum + 128 sq)
    if (i >= NN * 32) return;
    int row = i >> 5, cg = i & 31;
    float4 v;
    if (flags[0]) {
        v = ((const float4*)y)[i];
    } else {
        ushort4 u = ((const ushort4*)y)[i];
        v = make_float4(bf2f(u.x), bf2f(u.y), bf2f(u.z), bf2f(u.w));
    }
    ushort4 o;
    o.x = f2bf(v.x); o.y = f2bf(v.y); o.z = f2bf(v.z); o.w = f2bf(v.w);
    *(ushort4*)&XC[(size_t)row * 512 + 4 * cg] = o;
}

// ---------- SpMM gather (128 cols): XC[ci,ci+128) -> XC[co,co+128) ----------
__global__ __launch_bounds__(256) void k_spmm(b16* __restrict__ XC, int ci, int co,
                                              const int* __restrict__ rowptr,
                                              const unsigned long long* __restrict__ pairs) {
    int gid = blockIdx.x * blockDim.x + threadIdx.x;
    int node = gid >> 6;
    if (node >= NN) return;
    int lane = gid & 63;
    int grp = lane >> 4;  // edge slot group 0..3
    int l15 = lane & 15;  // 16B chunk within 256B segment
    int beg = rowptr[node], end = rowptr[node + 1];

    float a0[8], a1[8];
#pragma unroll
    for (int j = 0; j < 8; ++j) {
        a0[j] = 0.f;
        a1[j] = 0.f;
    }
    for (int i = beg; i < end; i += 8) {
        int e0 = i + grp, e1 = e0 + 4;
        int lim = end - 1;
        unsigned long long p0 = pairs[e0 < lim ? e0 : lim];
        unsigned long long p1 = pairs[e1 < lim ? e1 : lim];
        float w0 = (e0 < end) ? __uint_as_float((unsigned)(p0 >> 32)) : 0.f;
        float w1 = (e1 < end) ? __uint_as_float((unsigned)(p1 >> 32)) : 0.f;
        int s0 = (int)(p0 & 0xffffffffu);
        int s1 = (int)(p1 & 0xffffffffu);
        us8 u0 = *(const us8*)&XC[(size_t)s0 * 512 + ci + 8 * l15];
        us8 u1 = *(const us8*)&XC[(size_t)s1 * 512 + ci + 8 * l15];
#pragma unroll
        for (int j = 0; j < 8; ++j) {
            a0[j] = fmaf(w0, bf2f(u0[j]), a0[j]);
            a1[j] = fmaf(w1, bf2f(u1[j]), a1[j]);
        }
    }
#pragma unroll
    for (int j = 0; j < 8; ++j) a0[j] += a1[j];
#pragma unroll
    for (int j = 0; j < 8; ++j) a0[j] += __shfl_xor(a0[j], 16);
#pragma unroll
    for (int j = 0; j < 8; ++j) a0[j] += __shfl_xor(a0[j], 32);
    if (grp == 0) {
        us8 o;
#pragma unroll
        for (int j = 0; j < 8; ++j) o[j] = f2bf(a0[j]);
        *(us8*)&XC[(size_t)node * 512 + co + 8 * l15] = o;
    }
}

// ---------- SpMM gather (64 cols) + fused z-add: D = A*G + Z[:,zoff..] ----------
__global__ __launch_bounds__(256) void k_spmm64(const b16* __restrict__ G, int gstride,
                                                int gcol, const b16* __restrict__ Z,
                                                int zoff, b16* __restrict__ D,
                                                const int* __restrict__ rowptr,
                                                const unsigned long long* __restrict__ pairs) {
    int gid = blockIdx.x * blockDim.x + threadIdx.x;
    int node = gid >> 6;
    if (node >= NN) return;
    int lane = gid & 63;
    int grp = lane >> 4;
    int l15 = lane & 15;  // 8B chunk (4 bf16) within 128B segment
    int beg = rowptr[node], end = rowptr[node + 1];

    float a0[4], a1[4];
#pragma unroll
    for (int j = 0; j < 4; ++j) {
        a0[j] = 0.f;
        a1[j] = 0.f;
    }
    for (int i = beg; i < end; i += 8) {
        int e0 = i + grp, e1 = e0 + 4;
        int lim = end - 1;
        unsigned long long p0 = pairs[e0 < lim ? e0 : lim];
        unsigned long long p1 = pairs[e1 < lim ? e1 : lim];
        float w0 = (e0 < end) ? __uint_as_float((unsigned)(p0 >> 32)) : 0.f;
        float w1 = (e1 < end) ? __uint_as_float((unsigned)(p1 >> 32)) : 0.f;
        int s0 = (int)(p0 & 0xffffffffu);
        int s1 = (int)(p1 & 0xffffffffu);
        ushort4 u0 = *(const ushort4*)&G[(size_t)s0 * gstride + gcol + 4 * l15];
        ushort4 u1 = *(const ushort4*)&G[(size_t)s1 * gstride + gcol + 4 * l15];
        a0[0] = fmaf(w0, bf2f(u0.x), a0[0]);
        a0[1] = fmaf(w0, bf2f(u0.y), a0[1]);
        a0[2] = fmaf(w0, bf2f(u0.z), a0[2]);
        a0[3] = fmaf(w0, bf2f(u0.w), a0[3]);
        a1[0] = fmaf(w1, bf2f(u1.x), a1[0]);
        a1[1] = fmaf(w1, bf2f(u1.y), a1[1]);
        a1[2] = fmaf(w1, bf2f(u1.z), a1[2]);
        a1[3] = fmaf(w1, bf2f(u1.w), a1[3]);
    }
#pragma unroll
    for (int j = 0; j < 4; ++j) a0[j] += a1[j];
#pragma unroll
    for (int j = 0; j < 4; ++j) a0[j] += __shfl_xor(a0[j], 16);
#pragma unroll
    for (int j = 0; j < 4; ++j) a0[j] += __shfl_xor(a0[j], 32);
    if (grp == 0) {
        ushort4 z = *(const ushort4*)&Z[(size_t)node * 256 + zoff + 4 * l15];
        ushort4 o;
        o.x = f2bf(a0[0] + bf2f(z.x));
        o.y = f2bf(a0[1] + bf2f(z.y));
        o.z = f2bf(a0[2] + bf2f(z.z));
        o.w = f2bf(a0[3] + bf2f(z.w));
        *(ushort4*)&D[(size_t)node * 64 + 4 * l15] = o;
    }
}

// ---------- MFMA GEMM + fused BN-stat epilogue (v0: proven best, 96 VGPR) ----
// Wave = 32 rows x NC cols; block = 4 waves = 128 rows; depth-1 reg prefetch.
// Five structural variants (16-row, col-split, LDS-dbuf, 64-row, LB-capped)
// all lost to this: hipcc won't keep >~96 live VGPRs of prefetch state.
template <int NC>
__global__ __launch_bounds__(256) void k_mgemm(const b16* __restrict__ XC,
                                               const b16* __restrict__ Wp,
                                               const float* __restrict__ bias,
                                               b16* __restrict__ OUT,
                                               float* __restrict__ gsum,
                                               float* __restrict__ gsq) {
    constexpr int CT = NC / 16;
    __shared__ float csum[NC], csq[NC];
    const int tid = threadIdx.x;
    const int wave = tid >> 6;
    const int lane = tid & 63;
    const int quad = lane >> 4;
    const int l15 = lane & 15;
    const int rbase = blockIdx.x * 128 + wave * 32;

    for (int i = tid; i < NC; i += 256) {
        csum[i] = 0.f;
        csq[i] = 0.f;
    }

    float4v acc[2][CT];
#pragma unroll
    for (int rt = 0; rt < 2; ++rt)
#pragma unroll
        for (int ct = 0; ct < CT; ++ct) acc[rt][ct] = (float4v)(0.f);

    const b16* gA[2];
#pragma unroll
    for (int rt = 0; rt < 2; ++rt) {
        int r = rbase + 16 * rt + l15;
        if (r >= NN) r = NN - 1;  // clamp; dead rows excluded from store/stats
        gA[rt] = XC + (size_t)r * 512 + quad * 8;
    }
    const b16* gB = Wp + lane * 8;

    short8 afc[2], bfc[CT], afn[2], bfn[CT];
#pragma unroll
    for (int rt = 0; rt < 2; ++rt) afc[rt] = *(const short8*)(gA[rt]);
#pragma unroll
    for (int ct = 0; ct < CT; ++ct) bfc[ct] = *(const short8*)(gB + ct * 512);

    for (int ks = 0; ks < 16; ++ks) {
        if (ks < 15) {  // prefetch next k-step into regs (issues before MFMA waits)
#pragma unroll
            for (int rt = 0; rt < 2; ++rt)
                afn[rt] = *(const short8*)(gA[rt] + 32 * (ks + 1));
#pragma unroll
            for (int ct = 0; ct < CT; ++ct)
                bfn[ct] = *(const short8*)(gB + (size_t)((ks + 1) * CT + ct) * 512);
        }
#pragma unroll
        for (int rt = 0; rt < 2; ++rt)
#pragma unroll
            for (int ct = 0; ct < CT; ++ct)
                acc[rt][ct] = __builtin_amdgcn_mfma_f32_16x16x32_bf16(
                    afc[rt], bfc[ct], acc[rt][ct], 0, 0, 0);
        if (ks < 15) {
#pragma unroll
            for (int rt = 0; rt < 2; ++rt) afc[rt] = afn[rt];
#pragma unroll
            for (int ct = 0; ct < CT; ++ct) bfc[ct] = bfn[ct];
        }
    }

    // epilogue: bf16 store + BN stats (C/D: col=lane&15, row=quad*4+reg)
#pragma unroll
    for (int rt = 0; rt < 2; ++rt) {
#pragma unroll
        for (int ct = 0; ct < CT; ++ct) {
            int col = 16 * ct + l15;
            float bv = bias ? bias[col] : 0.f;
            float s = 0.f, sq = 0.f;
#pragma unroll
            for (int r = 0; r < 4; ++r) {
                int row = rbase + 16 * rt + quad * 4 + r;
                if (row < NN) {
                    float v = acc[rt][ct][r] + bv;
                    OUT[(size_t)row * NC + col] = f2bf(v);
                    s += v;
                    sq += v * v;
                }
            }
            s += __shfl_xor(s, 16);
            s += __shfl_xor(s, 32);
            sq += __shfl_xor(sq, 16);
            sq += __shfl_xor(sq, 32);
            if (quad == 0) {
                atomicAdd(&csum[col], s);
                atomicAdd(&csq[col], sq);
            }
        }
    }
    __syncthreads();
    for (int i = tid; i < NC; i += 256) {
        unsafeAtomicAdd(&gsum[i], csum[i]);
        unsafeAtomicAdd(&gsq[i], csq[i]);
    }
}

// ---------- fused BN(layer2) + Z-GEMM: Z = lrelu(BN(OUT)) @ Bp ----------
// XC[:,0:128) after layer-2 bnapply was consumed ONLY by zgemm, so the BN +
// LeakyReLU moves into zgemm's A-load: read OUT (pre-BN), apply scale/shift
// (computed per block from gsum/gsq in LDS, same formula as k_bnapply_mid),
// round to bf16 at the same point as before (numerically identical), MFMA.
// Saves the bnapply dispatch + 51 MB XC write+read traffic.
__global__ __launch_bounds__(256) void k_zgemm_f(
    const b16* __restrict__ OUT, const float* __restrict__ gsum,
    const float* __restrict__ gsq, const float* __restrict__ g,
    const float* __restrict__ be, const b16* __restrict__ Bp,
    b16* __restrict__ Z) {
    __shared__ float sc[128], sh[128];
    const int tid = threadIdx.x;
    if (tid < 128) {
        float m = gsum[tid] * (1.f / NN);
        float v = gsq[tid] * (1.f / NN) - m * m;
        v = fmaxf(v, 0.f);
        float s = rsqrtf(v + 1e-5f) * g[tid];
        sc[tid] = s;
        sh[tid] = be[tid] - m * s;
    }
    __syncthreads();

    const int wave = tid >> 6;
    const int lane = tid & 63;
    const int quad = lane >> 4;
    const int l15 = lane & 15;
    const int wr = wave >> 1;
    const int wc = wave & 1;
    const int rbase = blockIdx.x * 64 + wr * 32;

    float4v acc[2][8];
#pragma unroll
    for (int rt = 0; rt < 2; ++rt)
#pragma unroll
        for (int ct = 0; ct < 8; ++ct) acc[rt][ct] = (float4v)(0.f);

    const b16* gA[2];
#pragma unroll
    for (int rt = 0; rt < 2; ++rt) {
        int r = rbase + 16 * rt + l15;
        if (r >= NN) r = NN - 1;
        gA[rt] = OUT + (size_t)r * 128 + quad * 8;
    }
    const b16* gB = Bp + ((size_t)(wc * 8) * 64 + lane) * 8;

    us8 arc[2], arn[2];
    short8 bfc[8], bfn[8];
#pragma unroll
    for (int rt = 0; rt < 2; ++rt) arc[rt] = *(const us8*)(gA[rt]);
#pragma unroll
    for (int ct = 0; ct < 8; ++ct) bfc[ct] = *(const short8*)(gB + ct * 512);

    for (int ks = 0; ks < 4; ++ks) {
        if (ks < 3) {
#pragma unroll
            for (int rt = 0; rt < 2; ++rt)
                arn[rt] = *(const us8*)(gA[rt] + 32 * (ks + 1));
#pragma unroll
            for (int ct = 0; ct < 8; ++ct)
                bfn[ct] = *(const short8*)(gB + (size_t)((ks + 1) * 16 + ct) * 512);
        }
        // BN + LeakyReLU on the A fragment (cols ks*32 + quad*8 + j)
        short8 af[2];
        const int cbase = ks * 32 + quad * 8;
#pragma unroll
        for (int rt = 0; rt < 2; ++rt) {
#pragma unroll
            for (int j = 0; j < 8; ++j) {
                float v = fmaf(bf2f(arc[rt][j]), sc[cbase + j], sh[cbase + j]);
                v = v > 0.f ? v : 0.01f * v;
                af[rt][j] = (short)f2bf(v);
            }
        }
#pragma unroll
        for (int rt = 0; rt < 2; ++rt)
#pragma unroll
            for (int ct = 0; ct < 8; ++ct)
                acc[rt][ct] = __builtin_amdgcn_mfma_f32_16x16x32_bf16(
                    af[rt], bfc[ct], acc[rt][ct], 0, 0, 0);
        if (ks < 3) {
#pragma unroll
            for (int rt = 0; rt < 2; ++rt) arc[rt] = arn[rt];
#pragma unroll
            for (int ct = 0; ct < 8; ++ct) bfc[ct] = bfn[ct];
        }
    }

#pragma unroll
    for (int rt = 0; rt < 2; ++rt) {
#pragma unroll
        for (int ct = 0; ct < 8; ++ct) {
            int col = 16 * (wc * 8 + ct) + l15;
#pragma unroll
            for (int r = 0; r < 4; ++r) {
                int row = rbase + 16 * rt + quad * 4 + r;
                if (row < NN) Z[(size_t)row * 256 + col] = f2bf(acc[rt][ct][r]);
            }
        }
    }
}

// ---------- column stats of compact NN x 64 bf16 buffer -> gsum/gsq ----------
__global__ __launch_bounds__(256) void k_stat64(const b16* __restrict__ T,
                                                float* __restrict__ gsum,
                                                float* __restrict__ gsq) {
    __shared__ float cs[64], cq[64];
    const int tid = threadIdx.x;
    if (tid < 64) { cs[tid] = 0.f; cq[tid] = 0.f; }
    __syncthreads();
    const int gt = blockIdx.x * 256 + tid;
    const int stride = gridDim.x * 256;  // multiple of 8 -> octet fixed per thread
    float s[8], q[8];
#pragma unroll
    for (int j = 0; j < 8; ++j) { s[j] = 0.f; q[j] = 0.f; }
    for (int ch = gt; ch < NN * 8; ch += stride) {
        us8 u = *(const us8*)&T[(size_t)ch * 8];
#pragma unroll
        for (int j = 0; j < 8; ++j) {
            float v = bf2f(u[j]);
            s[j] += v;
            q[j] += v * v;
        }
    }
#pragma unroll
    for (int j = 0; j < 8; ++j) {
        s[j] += __shfl_xor(s[j], 8);
        s[j] += __shfl_xor(s[j], 16);
        s[j] += __shfl_xor(s[j], 32);
        q[j] += __shfl_xor(q[j], 8);
        q[j] += __shfl_xor(q[j], 16);
        q[j] += __shfl_xor(q[j], 32);
    }
    const int lane = tid & 63;
    if (lane < 8) {
        const int c0 = lane * 8;  // lane&7 == octet id after butterfly
#pragma unroll
        for (int j = 0; j < 8; ++j) {
            atomicAdd(&cs[c0 + j], s[j]);
            atomicAdd(&cq[c0 + j], q[j]);
        }
    }
    __syncthreads();
    if (tid < 64) {
        unsafeAtomicAdd(&gsum[tid], cs[tid]);
        unsafeAtomicAdd(&gsq[tid], cq[tid]);
    }
}

// ---------- BN-apply layer 1 (fused param compute): OUT -> XC cols [0,128) ----
__global__ __launch_bounds__(256) void k_bnapply_mid(
    const b16* __restrict__ OUT, const float* __restrict__ gsum,
    const float* __restrict__ gsq, const float* __restrict__ g,
    const float* __restrict__ be, b16* __restrict__ XC) {
    __shared__ float sc[128], sh[128];
    const int tid = threadIdx.x;
    if (tid < 128) {
        float m = gsum[tid] * (1.f / NN);
        float v = gsq[tid] * (1.f / NN) - m * m;
        v = fmaxf(v, 0.f);
        float s = rsqrtf(v + 1e-5f) * g[tid];
        sc[tid] = s;
        sh[tid] = be[tid] - m * s;
    }
    __syncthreads();
    int i = blockIdx.x * 256 + tid;
    if (i >= NN * 16) return;
    int row = i >> 4, c0 = (i & 15) * 8;
    us8 u = *(const us8*)&OUT[(size_t)row * 128 + c0];
    us8 o;
#pragma unroll
    for (int j = 0; j < 8; ++j) {
        float a = fmaf(bf2f(u[j]), sc[c0 + j], sh[c0 + j]);
        a = a > 0.f ? a : 0.01f * a;
        o[j] = f2bf(a);
    }
    *(us8*)&XC[(size_t)row * 512 + c0] = o;
}

// ---------- BN-apply layer 3 (fused param compute): T (NN x 64) -> d_out ----------
__global__ __launch_bounds__(256) void k_bnapply_last(
    const b16* __restrict__ T, const float* __restrict__ gsum,
    const float* __restrict__ gsq, const float* __restrict__ g,
    const float* __restrict__ be, void* __restrict__ dout,
    const int* __restrict__ flags) {
    __shared__ float sc[64], sh[64];
    const int tid = threadIdx.x;
    if (tid < 64) {
        float m = gsum[tid] * (1.f / NN);
        float v = gsq[tid] * (1.f / NN) - m * m;
        v = fmaxf(v, 0.f);
        float s = rsqrtf(v + 1e-5f) * g[tid];
        sc[tid] = s;
        sh[tid] = be[tid] - m * s;
    }
    __syncthreads();
    int i = blockIdx.x * 256 + tid;
    if (i >= NN * 8) return;
    int c0 = (i & 7) * 8;
    us8 u = *(const us8*)&T[(size_t)i * 8];
    float v[8];
#pragma unroll
    for (int j = 0; j < 8; ++j) {
        float a = fmaf(bf2f(u[j]), sc[c0 + j], sh[c0 + j]);
        v[j] = a > 0.f ? a : 0.01f * a;
    }
    if (flags[0]) {
        float4* d = (float4*)dout;
        d[i * 2] = make_float4(v[0], v[1], v[2], v[3]);
        d[i * 2 + 1] = make_float4(v[4], v[5], v[6], v[7]);
    } else {
        us8 o;
#pragma unroll
        for (int j = 0; j < 8; ++j) o[j] = f2bf(v[j]);
        *(us8*)&((b16*)dout)[(size_t)i * 8] = o;
    }
}

// ---------- driver ----------
extern "C" void kernel_launch(void* const* d_in, const int* in_sizes, int n_in,
                              void* d_out, int out_size, void* d_ws, size_t ws_size,
                              hipStream_t stream) {
    const void* y   = d_in[0];
    const void* ei  = d_in[1];
    const void* ea  = d_in[2];
    const void* W1  = d_in[3];
    const void* b1  = d_in[4];
    const void* g1  = d_in[5];
    const void* be1 = d_in[6];
    const void* W2  = d_in[7];
    const void* b2  = d_in[8];
    const void* g2  = d_in[9];
    const void* be2 = d_in[10];
    const void* W3  = d_in[11];
    const void* g3  = d_in[12];
    const void* be3 = d_in[13];

    char* w = (char*)d_ws;
    size_t used = 0;
    auto carve = [&](size_t bytes) -> char* {
        char* p = w + used;
        used += (bytes + 255) & ~(size_t)255;
        return p;
    };

    int* flags   = (int*)carve(16);
    int* src32   = (int*)carve((size_t)NE * 4);
    int* dst32   = (int*)carve((size_t)NE * 4);
    float* deg   = (float*)carve((size_t)NN * 4);
    int* cnt     = (int*)carve((size_t)NN * 4);
    int* rowptr  = (int*)carve((size_t)(NN + 1) * 4);
    int* cscan   = (int*)carve((size_t)NN * 4);
    int* bsum    = (int*)carve((size_t)SCAN_NB * 4);
    unsigned long long* pairs = (unsigned long long*)carve((size_t)NE * 8);
    float* PB    = (float*)carve(PB_SZ * 4);
    b16* Wp1     = (b16*)carve((size_t)512 * 128 * 2);
    b16* Wp2     = (b16*)carve((size_t)512 * 128 * 2);
    b16* Wp3c    = (b16*)carve((size_t)128 * 256 * 2);
    b16* OUT     = (b16*)carve((size_t)NN * 128 * 2);
    float* gstat = (float*)carve(768 * 4);  // 3 layers x (128 sum + 128 sq)
    b16* XC      = (b16*)carve((size_t)NN * 512 * 2);
    b16* Z       = (b16*)carve((size_t)NN * 256 * 2);  // z0|z1|z2|z3 (64 cols each)
    b16* T0      = (b16*)carve((size_t)NN * 64 * 2);
    b16* T1      = (b16*)carve((size_t)NN * 64 * 2);

    // ----- fused detect + param normalize; weight pack -----
    k_cvtall<<<1, 1024, 0, stream>>>(y, ei, b1, b2, g1, be1, g2, be2, g3, be3, PB,
                                     flags);
    k_pack<<<(512 * 128 / 8 + 255) / 256, 256, 0, stream>>>(W1, Wp1, 128, flags);
    k_pack<<<(512 * 128 / 8 + 255) / 256, 256, 0, stream>>>(W2, Wp2, 128, flags);
    k_pack3<<<16, 256, 0, stream>>>(W3, Wp3c, flags);

    // ----- graph prep -----
    k_idx<<<(NE + 255) / 256, 256, 0, stream>>>(ei, src32, dst32, flags, deg, cnt);
    k_degcnt<<<(NE + 255) / 256, 256, 0, stream>>>(dst32, ea, deg, cnt, flags);
    k_scan1<<<SCAN_NB, SCAN_B, 0, stream>>>(cnt, cscan, bsum, deg);
    k_scan3<<<SCAN_NB, SCAN_B, 0, stream>>>(cscan, bsum, rowptr, cnt);
    k_fill<<<(NE + 255) / 256, 256, 0, stream>>>(src32, dst32, ea, deg, rowptr, cnt,
                                                 pairs, flags);

    // ----- layers -----
    k_cast<<<(NN * 32 + 255) / 256, 256, 0, stream>>>(y, XC, flags, gstat);

    const int spmm_grid = (NN * 64 + 255) / 256;
    auto spmm = [&](int ci, int co) {
        k_spmm<<<spmm_grid, 256, 0, stream>>>(XC, ci, co, rowptr, pairs);
    };
    const int gemm_grid = (NN + 127) / 128;

    // layer 1: hops + GEMM + BN-apply into XC[:,0:128)
    float* gs1 = gstat;
    float* gq1 = gstat + 128;
    spmm(0, 128);
    spmm(128, 256);
    spmm(256, 384);
    k_mgemm<128><<<gemm_grid, 256, 0, stream>>>(XC, Wp1, PB + PB_B1, OUT, gs1, gq1);
    k_bnapply_mid<<<(NN * 16 + 255) / 256, 256, 0, stream>>>(OUT, gs1, gq1, PB + PB_G1,
                                                             PB + PB_BE1, XC);

    // layer 2: hops + GEMM; BN-apply is FUSED into the layer-3 zgemm A-load
    float* gs2 = gstat + 256;
    float* gq2 = gstat + 384;
    spmm(0, 128);
    spmm(128, 256);
    spmm(256, 384);
    k_mgemm<128><<<gemm_grid, 256, 0, stream>>>(XC, Wp2, PB + PB_B2, OUT, gs2, gq2);

    // layer 3 (Horner): z=[z0..z3]=lrelu(BN(OUT))@W3cat; h=z3; h=A*h+z2; ...
    k_zgemm_f<<<(NN + 63) / 64, 256, 0, stream>>>(OUT, gs2, gq2, PB + PB_G2,
                                                  PB + PB_BE2, Wp3c, Z);
    k_spmm64<<<spmm_grid, 256, 0, stream>>>(Z, 256, 192, Z, 128, T0, rowptr, pairs);
    k_spmm64<<<spmm_grid, 256, 0, stream>>>(T0, 64, 0, Z, 64, T1, rowptr, pairs);
    k_spmm64<<<spmm_grid, 256, 0, stream>>>(T1, 64, 0, Z, 0, T0, rowptr, pairs);
    float* gs3 = gstat + 512;
    float* gq3 = gstat + 640;
    k_stat64<<<256, 256, 0, stream>>>(T0, gs3, gq3);
    k_bnapply_last<<<(NN * 8 + 255) / 256, 256, 0, stream>>>(T0, gs3, gq3, PB + PB_G3,
                                                             PB + PB_BE3, d_out, flags);
}